// Round 13
// baseline (79.831 us; speedup 1.0000x reference)
//
#include <hip/hip_runtime.h>

#define EDIM 256
#define HDIM 256

typedef float v2f __attribute__((ext_vector_type(2)));
__device__ __forceinline__ v2f splat2(float x) { v2f r; r.x = x; r.y = x; return r; }
__device__ __forceinline__ v2f mk2(float a, float b) { v2f r; r.x = a; r.y = b; return r; }
__device__ __forceinline__ v2f pkfma(v2f a, v2f b, v2f c) { return __builtin_elementwise_fma(a, b, c); }

__device__ __forceinline__ float waveAllSum(float v) {
  #pragma unroll
  for (int m = 32; m >= 1; m >>= 1) v += __shfl_xor(v, m, 64);
  return v;
}

// ---------------------------------------------------------------------------
// K1: row-matmuls, 8 rows/block.
//  which 0..5: P/Q projections + CA/CB (biases folded: rel_b1->P, cor_b1->CB)
//  which 6: Ca = rel_W2 @ mapWa  (x<32), da = rel_b2 @ mapWa (x==32)
//  which 7: Cb = rel_W2 @ mapWb  (x<32), db = rel_b2 @ mapWb (x==32)
// ---------------------------------------------------------------------------
__global__ __launch_bounds__(256) void k_proj(
    const float* __restrict__ srcE, const float* __restrict__ tgtE,
    const float* __restrict__ relW1, const float* __restrict__ relb1,
    const float* __restrict__ corW1, const float* __restrict__ corb1,
    const float* __restrict__ relW2, const float* __restrict__ relb2,
    const float* __restrict__ mapW1,
    float* __restrict__ Ps, float* __restrict__ Qs,
    float* __restrict__ Pt, float* __restrict__ Qt,
    float* __restrict__ CA, float* __restrict__ CB,
    float* __restrict__ Ca, float* __restrict__ Cb,
    float* __restrict__ da, float* __restrict__ db)
{
  const int which = blockIdx.y;       // 0..7
  const int xb    = blockIdx.x;
  const int h     = threadIdx.x;
  if (which < 6 && xb >= 16) return;
  const int row0  = xb * 8;

  const float* A = nullptr; const float* W; const float* bias = nullptr;
  float* out;
  if (which == 0)      { A = srcE; W = relW1;              bias = relb1; out = Ps; }
  else if (which == 1) { A = srcE; W = relW1 + EDIM*HDIM;  out = Qs; }
  else if (which == 2) { A = tgtE; W = relW1;              bias = relb1; out = Pt; }
  else if (which == 3) { A = tgtE; W = relW1 + EDIM*HDIM;  out = Qt; }
  else if (which == 4) { A = srcE; W = corW1;              out = CA; }
  else if (which == 5) { A = tgtE; W = corW1 + EDIM*HDIM;  bias = corb1; out = CB; }
  else if (which == 6) { W = mapW1;                        out = Ca; }
  else                 { W = mapW1 + EDIM*HDIM;            out = Cb; }

  __shared__ float arow[8][EDIM];
  if (which < 6) {
    #pragma unroll
    for (int r = 0; r < 8; ++r) arow[r][h] = A[(row0 + r)*EDIM + h];
  } else if (xb < 32) {
    #pragma unroll
    for (int r = 0; r < 8; ++r) arow[r][h] = relW2[(row0 + r)*EDIM + h];
  } else {
    #pragma unroll
    for (int r = 0; r < 8; ++r) arow[r][h] = relb2[h];
  }
  __syncthreads();

  float acc[8];
  const float init = bias ? bias[h] : 0.0f;
  #pragma unroll
  for (int r = 0; r < 8; ++r) acc[r] = init;

  for (int d = 0; d < EDIM; d += 4) {
    const float w0 = W[(d+0)*HDIM + h];
    const float w1 = W[(d+1)*HDIM + h];
    const float w2 = W[(d+2)*HDIM + h];
    const float w3 = W[(d+3)*HDIM + h];
    #pragma unroll
    for (int r = 0; r < 8; ++r) {
      const float4 av = *(const float4*)&arow[r][d];
      acc[r] = fmaf(av.x,w0, fmaf(av.y,w1, fmaf(av.z,w2, fmaf(av.w,w3, acc[r]))));
    }
  }

  if (which < 6 || xb < 32) {
    #pragma unroll
    for (int r = 0; r < 8; ++r) out[(row0 + r)*HDIM + h] = acc[r];
  } else {
    float* d = (which == 6) ? da : db;
    d[h] = acc[0];
  }
}

// ---------------------------------------------------------------------------
// K2: fused rel-encode + combined projection, 8 rows/block, 512 threads.
// rg = tid>>8 owns 4 rows; both row-groups issue IDENTICAL C addresses
// (L1 reuse). Single GEMM vs precombined C = W2 @ mapW{a,b}:
//   X = relu(LN(P+Q));  out = m_row * (X@C + d) [+ mapb1 for side1]
// Epilogue: row stats; side0 -> SAp (packed s-pairs) + SAr; side1 -> TB.
// ---------------------------------------------------------------------------
__global__ __launch_bounds__(512) void k_encode(
    const float* __restrict__ Ps, const float* __restrict__ Qs,
    const float* __restrict__ relS,
    const float* __restrict__ Pt, const float* __restrict__ Qt,
    const float* __restrict__ relT,
    const float* __restrict__ g1, const float* __restrict__ be1,
    const float* __restrict__ Ca, const float* __restrict__ Cb,
    const float* __restrict__ da, const float* __restrict__ db,
    const float* __restrict__ mapb1,
    const float* __restrict__ mapg, const float* __restrict__ mapbe,
    const float* __restrict__ mapW2,
    float2* __restrict__ SAp, float* __restrict__ SAr, float* __restrict__ TB,
    float* __restrict__ rsS, float* __restrict__ qsS,
    float* __restrict__ rsT, float* __restrict__ qsT,
    float4* __restrict__ gbw)
{
  const int side = blockIdx.y;
  const float* P   = side ? Pt   : Ps;
  const float* Q   = side ? Qt   : Qs;
  const float* rel = side ? relT : relS;

  const int row0 = blockIdx.x * 8;      // [0,2048)
  const int b   = row0 >> 8;
  const int ij0 = row0 & 255;
  const int i   = ij0 >> 4;
  const int j0  = ij0 & 15;             // 8 consecutive j, same i
  const int tid  = threadIdx.x;
  const int h    = tid & 255;
  const int rg   = tid >> 8;            // row-group: rows rg*4 .. rg*4+3
  const int wave = tid >> 6;            // 0..7
  const int lane = tid & 63;

  if (side == 0 && blockIdx.x == 0 && rg == 0)
    gbw[h] = make_float4(mapg[h], mapbe[h], mapW2[h], 0.0f);

  __shared__ v2f rlp[2][2][HDIM];       // [rg][pair][h], 8 KB
  __shared__ float red[8][8];

  const float pv = P[(b*16 + i)*HDIM + h];
  float x[4];
  #pragma unroll
  for (int r = 0; r < 4; ++r) x[r] = pv + Q[(b*16 + j0 + rg*4 + r)*HDIM + h];

  // LN stats
  {
    float s1[4], s2[4];
    #pragma unroll
    for (int r = 0; r < 4; ++r) { s1[r] = x[r]; s2[r] = x[r]*x[r]; }
    #pragma unroll
    for (int m = 32; m >= 1; m >>= 1) {
      #pragma unroll
      for (int r = 0; r < 4; ++r) {
        s1[r] += __shfl_xor(s1[r], m, 64);
        s2[r] += __shfl_xor(s2[r], m, 64);
      }
    }
    if (lane == 0) {
      #pragma unroll
      for (int r = 0; r < 4; ++r) { red[wave][2*r] = s1[r]; red[wave][2*r+1] = s2[r]; }
    }
  }
  __syncthreads();

  {
    const float gh = g1[h], beh = be1[h];
    const int wb = rg*4;
    float val[4];
    #pragma unroll
    for (int r = 0; r < 4; ++r) {
      const float S1 = red[wb+0][2*r] + red[wb+1][2*r] + red[wb+2][2*r] + red[wb+3][2*r];
      const float S2 = red[wb+0][2*r+1] + red[wb+1][2*r+1] + red[wb+2][2*r+1] + red[wb+3][2*r+1];
      const float mean = S1 * (1.0f/256.0f);
      const float var  = S2 * (1.0f/256.0f) - mean*mean;
      const float rinv = rsqrtf(var + 1e-5f);
      val[r] = fmaxf(fmaf((x[r] - mean)*rinv, gh, beh), 0.0f);
    }
    rlp[rg][0][h] = mk2(val[0], val[1]);
    rlp[rg][1][h] = mk2(val[2], val[3]);
  }
  __syncthreads();

  // single GEMM vs precombined C
  const float* C = side ? Cb : Ca;
  v2f c01 = {0.f,0.f}, c23 = {0.f,0.f};
  #pragma unroll 2
  for (int k = 0; k < HDIM; k += 4) {
    const float w0 = C[(k+0)*HDIM + h];
    const float w1 = C[(k+1)*HDIM + h];
    const float w2 = C[(k+2)*HDIM + h];
    const float w3 = C[(k+3)*HDIM + h];
    const float4 pa = *(const float4*)&rlp[rg][0][k];
    const float4 pb = *(const float4*)&rlp[rg][0][k+2];
    const float4 qa = *(const float4*)&rlp[rg][1][k];
    const float4 qb = *(const float4*)&rlp[rg][1][k+2];
    c01 = pkfma(mk2(pa.x,pa.y), splat2(w0), c01);
    c01 = pkfma(mk2(pa.z,pa.w), splat2(w1), c01);
    c01 = pkfma(mk2(pb.x,pb.y), splat2(w2), c01);
    c01 = pkfma(mk2(pb.z,pb.w), splat2(w3), c01);
    c23 = pkfma(mk2(qa.x,qa.y), splat2(w0), c23);
    c23 = pkfma(mk2(qa.z,qa.w), splat2(w1), c23);
    c23 = pkfma(mk2(qb.x,qb.y), splat2(w2), c23);
    c23 = pkfma(mk2(qb.z,qb.w), splat2(w3), c23);
  }

  {
    const float dv = (side ? db : da)[h];
    c01 = c01 + splat2(dv);
    c23 = c23 + splat2(dv);
    const float* relRow = rel + (b*16 + i)*16;
    const int jb = j0 + rg*4;
    const v2f m01 = mk2(relRow[jb+0] > 0.f ? 1.f : 0.f, relRow[jb+1] > 0.f ? 1.f : 0.f);
    const v2f m23 = mk2(relRow[jb+2] > 0.f ? 1.f : 0.f, relRow[jb+3] > 0.f ? 1.f : 0.f);
    c01 = c01 * m01;
    c23 = c23 * m23;
    if (side) {
      const float mb = mapb1[h];
      c01 = c01 + splat2(mb);
      c23 = c23 + splat2(mb);
    }
  }

  // row stats of output
  {
    float s1[4] = {c01.x, c01.y, c23.x, c23.y};
    float s2[4] = {c01.x*c01.x, c01.y*c01.y, c23.x*c23.x, c23.y*c23.y};
    #pragma unroll
    for (int m = 32; m >= 1; m >>= 1) {
      #pragma unroll
      for (int r = 0; r < 4; ++r) {
        s1[r] += __shfl_xor(s1[r], m, 64);
        s2[r] += __shfl_xor(s2[r], m, 64);
      }
    }
    __syncthreads();                    // red safe to rewrite
    if (lane == 0) {
      #pragma unroll
      for (int r = 0; r < 4; ++r) { red[wave][2*r] = s1[r]; red[wave][2*r+1] = s2[r]; }
    }
  }
  __syncthreads();
  if (tid < 16) {
    const int rg2 = tid >> 3, idx = tid & 7, r = idx >> 1;
    const int wb = rg2*4;
    const float v = red[wb+0][idx] + red[wb+1][idx] + red[wb+2][idx] + red[wb+3][idx];
    float* rs = side ? rsT : rsS;
    float* qs = side ? qsT : qsS;
    const int row = row0 + rg2*4 + r;
    if (idx & 1) qs[row] = v; else rs[row] = v;
  }

  const int rbase = row0 + rg*4;
  if (side == 0) {
    const int spBase = b*128 + ((ij0 + rg*4) >> 1);
    SAp[(spBase + 0)*HDIM + h] = make_float2(c01.x, c01.y);
    SAp[(spBase + 1)*HDIM + h] = make_float2(c23.x, c23.y);
    SAr[(rbase + 0)*HDIM + h] = c01.x;
    SAr[(rbase + 1)*HDIM + h] = c01.y;
    SAr[(rbase + 2)*HDIM + h] = c23.x;
    SAr[(rbase + 3)*HDIM + h] = c23.y;
  } else {
    TB[(rbase + 0)*HDIM + h] = c01.x;
    TB[(rbase + 1)*HDIM + h] = c01.y;
    TB[(rbase + 2)*HDIM + h] = c23.x;
    TB[(rbase + 3)*HDIM + h] = c23.y;
  }
}

// ---------------------------------------------------------------------------
// K3: cross GEMM G[b][t][s] = SAr[b,s,:] . TB[b,t,:]. 32x32 tile/block.
// XCD-clustered: b = idx & 7.
// ---------------------------------------------------------------------------
__global__ __launch_bounds__(256) void k_cross(
    const float* __restrict__ SAr, const float* __restrict__ TB,
    float* __restrict__ G)
{
  const int b    = blockIdx.x & 7;
  const int rest = blockIdx.x >> 3;     // [0,64)
  const int s0 = (rest & 7) * 32;
  const int t0 = (rest >> 3) * 32;
  const int tx = threadIdx.x & 15;      // s-sub
  const int ty = threadIdx.x >> 4;      // t-sub

  const float* SAb = SAr + ((b<<8) + s0)*HDIM;
  const float* TBb = TB  + ((b<<8) + t0)*HDIM;

  __shared__ float As[32][68], Bs[32][68];
  float acc00 = 0.f, acc01 = 0.f, acc10 = 0.f, acc11 = 0.f;

  const int lr = threadIdx.x >> 3;        // 0..31
  const int lc = (threadIdx.x & 7) * 8;   // 0..56

  for (int kk = 0; kk < HDIM; kk += 64) {
    *(float4*)&As[lr][lc]   = *(const float4*)&SAb[lr*HDIM + kk + lc];
    *(float4*)&As[lr][lc+4] = *(const float4*)&SAb[lr*HDIM + kk + lc + 4];
    *(float4*)&Bs[lr][lc]   = *(const float4*)&TBb[lr*HDIM + kk + lc];
    *(float4*)&Bs[lr][lc+4] = *(const float4*)&TBb[lr*HDIM + kk + lc + 4];
    __syncthreads();
    #pragma unroll
    for (int k = 0; k < 64; k += 4) {
      const float4 a0 = *(const float4*)&As[tx][k];
      const float4 a1 = *(const float4*)&As[tx+16][k];
      const float4 b0 = *(const float4*)&Bs[ty][k];
      const float4 b1 = *(const float4*)&Bs[ty+16][k];
      acc00 = fmaf(a0.x,b0.x, fmaf(a0.y,b0.y, fmaf(a0.z,b0.z, fmaf(a0.w,b0.w, acc00))));
      acc01 = fmaf(a0.x,b1.x, fmaf(a0.y,b1.y, fmaf(a0.z,b1.z, fmaf(a0.w,b1.w, acc01))));
      acc10 = fmaf(a1.x,b0.x, fmaf(a1.y,b0.y, fmaf(a1.z,b0.z, fmaf(a1.w,b0.w, acc10))));
      acc11 = fmaf(a1.x,b1.x, fmaf(a1.y,b1.y, fmaf(a1.z,b1.z, fmaf(a1.w,b1.w, acc11))));
    }
    __syncthreads();
  }

  float* Gb = G + (((b<<8) + t0)<<8) + s0;     // G[b][t][s]
  Gb[(ty   )*256 + tx     ] = acc00;
  Gb[(ty   )*256 + tx + 16] = acc10;
  Gb[(ty+16)*256 + tx     ] = acc01;
  Gb[(ty+16)*256 + tx + 16] = acc11;
}

// ---------------------------------------------------------------------------
// K4: fused scores, 256-thread blocks (4 waves), LDS-chunked TB stream.
// Blocks [0,512): mapping, XCD-clustered (b = blockIdx & 7). Block=(b,4 s).
//   Per 32-h chunk: cooperative COALESCED stage of TB[256t][32h] into LDS
//   (8 indep float4 loads/thread = 8-deep MLP), then 32 LDS iterations
//   (tbs[t][hh], pad 33 -> bank (t+hh)%32, conflict-free). SAp/gbw on the
//   scalar path (h0+hh uniform). Softmax fused in-block.
// Blocks [512,544): corr scores, wave = one (b,s), softmax over 16.
// map_b2 / cor_b2 cancel in softmax -> dropped.
// ---------------------------------------------------------------------------
__global__ __launch_bounds__(256) void k_scores(
    const float2* __restrict__ SApf, const float* __restrict__ TB,
    const float* __restrict__ G,
    const float* __restrict__ rsS, const float* __restrict__ qsS,
    const float* __restrict__ rsT, const float* __restrict__ qsT,
    const float4* __restrict__ gbw,
    const float* __restrict__ CA, const float* __restrict__ CB,
    const float* __restrict__ cW2,
    float* __restrict__ mapOut, float* __restrict__ corOut)
{
  const int wave = threadIdx.x >> 6;
  const int lane = threadIdx.x & 63;

  if (blockIdx.x >= 512) {
    const int bs = (blockIdx.x - 512)*4 + wave;
    const int b  = bs >> 4;
    const float4 ca4 = *(const float4*)(CA + bs*HDIM + lane*4);
    const float4 w24 = *(const float4*)(cW2 + lane*4);
    float sc[16];
    #pragma unroll
    for (int t = 0; t < 16; ++t) {
      const float4 cb4 = *(const float4*)(CB + (b*16 + t)*HDIM + lane*4);
      float p = fmaxf(ca4.x + cb4.x, 0.0f)*w24.x
              + fmaxf(ca4.y + cb4.y, 0.0f)*w24.y
              + fmaxf(ca4.z + cb4.z, 0.0f)*w24.z
              + fmaxf(ca4.w + cb4.w, 0.0f)*w24.w;
      sc[t] = waveAllSum(p);
    }
    float mx = sc[0];
    #pragma unroll
    for (int t = 1; t < 16; ++t) mx = fmaxf(mx, sc[t]);
    float se = 0.0f;
    #pragma unroll
    for (int t = 0; t < 16; ++t) { sc[t] = __expf(sc[t] - mx); se += sc[t]; }
    if (lane < 16) corOut[bs*16 + lane] = sc[lane] / se;
    return;
  }

  // XCD-clustered decode: batch = low 3 bits -> one XCD per batch
  const int b  = blockIdx.x & 7;
  const int s0 = (blockIdx.x >> 3) * 4;      // [0,256) step 4
  const int t  = (wave << 6) + lane;

  const v2f* sp0 = (const v2f*)SApf + ((b<<7) + (s0>>1))*HDIM;
  const v2f* sp1 = sp0 + HDIM;

  v2f al01, bt01, al23, bt23;
  {
    const float4 gv = *(const float4*)&G[(((b<<8) + t)<<8) + s0];
    const float rt = rsT[(b<<8) + t];
    const float qt = qsT[(b<<8) + t];
    const float Gv[4] = {gv.x, gv.y, gv.z, gv.w};
    float alv[4], btv[4];
    #pragma unroll
    for (int si = 0; si < 4; ++si) {
      const float mean = (rsS[(b<<8) + s0 + si] + rt) * (1.0f/256.0f);
      const float e2   = (qsS[(b<<8) + s0 + si] + qt + 2.0f*Gv[si]) * (1.0f/256.0f);
      const float rinv = rsqrtf(e2 - mean*mean + 1e-5f);
      alv[si] = rinv;
      btv[si] = -mean * rinv;
    }
    al01 = mk2(alv[0], alv[1]); bt01 = mk2(btv[0], btv[1]);
    al23 = mk2(alv[2], alv[3]); bt23 = mk2(btv[2], btv[3]);
  }

  __shared__ float tbs[256][33];               // 33.8 KB, pad -> conflict-free
  const float* TBbase = TB + (b << 16);        // TB[b][t][h]
  const int seg  = threadIdx.x & 7;            // h-segment (16B)
  const int trow = threadIdx.x >> 3;           // 0..31

  v2f acc01 = {0.f,0.f}, acc23 = {0.f,0.f};
  const v2f zero = {0.f,0.f};

  for (int h0 = 0; h0 < HDIM; h0 += 32) {
    __syncthreads();                           // prev chunk's reads done
    // coalesced stage: 8 rows/wave/pass, 8 passes
    #pragma unroll
    for (int p = 0; p < 8; ++p) {
      const int tr = trow + p*32;
      const float4 v = *(const float4*)&TBbase[tr*HDIM + h0 + seg*4];
      float* dst = &tbs[tr][seg*4];
      dst[0] = v.x; dst[1] = v.y; dst[2] = v.z; dst[3] = v.w;
    }
    __syncthreads();

    #pragma unroll 4
    for (int hh = 0; hh < 32; ++hh) {
      const int h = h0 + hh;                   // uniform -> scalar path
      const float tb = tbs[t][hh];
      const v2f a = sp0[h];
      const v2f c = sp1[h];
      const float4 q = gbw[h];
      v2f u, r;
      u = pkfma(a + splat2(tb), al01, bt01);
      r = __builtin_elementwise_max(pkfma(u, splat2(q.x), splat2(q.y)), zero);
      acc01 = pkfma(r, splat2(q.z), acc01);
      u = pkfma(c + splat2(tb), al23, bt23);
      r = __builtin_elementwise_max(pkfma(u, splat2(q.x), splat2(q.y)), zero);
      acc23 = pkfma(r, splat2(q.z), acc23);
    }
  }

  // softmax over t (256) for each of the 4 s
  __shared__ float sc[4][256];
  sc[0][t] = acc01.x; sc[1][t] = acc01.y; sc[2][t] = acc23.x; sc[3][t] = acc23.y;
  __syncthreads();

  float v0 = sc[wave][lane];
  float v1 = sc[wave][lane + 64];
  float v2 = sc[wave][lane + 128];
  float v3 = sc[wave][lane + 192];
  float mx = fmaxf(fmaxf(v0, v1), fmaxf(v2, v3));
  #pragma unroll
  for (int m = 32; m >= 1; m >>= 1) mx = fmaxf(mx, __shfl_xor(mx, m, 64));
  const float e0 = __expf(v0 - mx), e1 = __expf(v1 - mx);
  const float e2 = __expf(v2 - mx), e3 = __expf(v3 - mx);
  const float se = waveAllSum(e0 + e1 + e2 + e3);
  const float inv = 1.0f / se;
  float* orow = mapOut + ((b<<8) + s0 + wave)*256;
  orow[lane]       = e0 * inv;
  orow[lane + 64]  = e1 * inv;
  orow[lane + 128] = e2 * inv;
  orow[lane + 192] = e3 * inv;
}

extern "C" void kernel_launch(void* const* d_in, const int* in_sizes, int n_in,
                              void* d_out, int out_size, void* d_ws, size_t ws_size,
                              hipStream_t stream) {
  const float* srcE  = (const float*)d_in[0];
  const float* srcR  = (const float*)d_in[1];
  const float* tgtE  = (const float*)d_in[2];
  const float* tgtR  = (const float*)d_in[3];
  const float* relW1 = (const float*)d_in[4];
  const float* relb1 = (const float*)d_in[5];
  const float* relg1 = (const float*)d_in[6];
  const float* relbe1= (const float*)d_in[7];
  const float* relW2 = (const float*)d_in[8];
  const float* relb2 = (const float*)d_in[9];
  const float* mapW1 = (const float*)d_in[10];
  const float* mapb1 = (const float*)d_in[11];
  const float* mapg  = (const float*)d_in[12];
  const float* mapbe = (const float*)d_in[13];
  const float* mapW2 = (const float*)d_in[14];
  const float* corW1 = (const float*)d_in[16];
  const float* corb1 = (const float*)d_in[17];
  const float* corW2 = (const float*)d_in[18];

  float* ws   = (float*)d_ws;
  float* Ps   = ws;                 // 32768 each
  float* Qs   = Ps   + 32768;
  float* Pt   = Qs   + 32768;
  float* Qt   = Pt   + 32768;
  float* CA   = Qt   + 32768;
  float* CB   = CA   + 32768;
  float2* SAp = (float2*)(CB + 32768);          // 262144 float2 = 524288 f
  float* SAr  = (float*)(SAp + 262144);         // 524288 f
  float* TB   = SAr + 524288;                   // 524288 f
  float* G    = TB  + 524288;                   // 524288 f
  float* rsS  = G + 524288;         // 2048
  float* qsS  = rsS + 2048;
  float* rsT  = qsS + 2048;
  float* qsT  = rsT + 2048;
  float4* gbw = (float4*)(qsT + 2048);          // 256 float4 = 1024 f
  float* Ca   = (float*)gbw + 1024;             // 65536
  float* Cb   = Ca + 65536;                     // 65536
  float* da   = Cb + 65536;                     // 256
  float* db   = da + 256;                       // 256

  float* mapOut = (float*)d_out;        // 524288
  float* corOut = mapOut + 524288;      // 2048

  k_proj<<<dim3(33, 8), 256, 0, stream>>>(srcE, tgtE, relW1, relb1, corW1, corb1,
                                          relW2, relb2, mapW1,
                                          Ps, Qs, Pt, Qt, CA, CB,
                                          Ca, Cb, da, db);
  k_encode<<<dim3(256, 2), 512, 0, stream>>>(Ps, Qs, srcR,
                                             Pt, Qt, tgtR,
                                             relg1, relbe1,
                                             Ca, Cb, da, db,
                                             mapb1, mapg, mapbe, mapW2,
                                             SAp, SAr, TB, rsS, qsS, rsT, qsT, gbw);
  k_cross<<<512, 256, 0, stream>>>(SAr, TB, G);
  k_scores<<<544, 256, 0, stream>>>(SAp, TB, G, rsS, qsS, rsT, qsT, gbw,
                                    CA, CB, corW2, mapOut, corOut);
}

// Round 14
// 68.597 us; speedup vs baseline: 1.1638x; 1.1638x over previous
//
#include <hip/hip_runtime.h>

#define EDIM 256
#define HDIM 256

typedef float v2f __attribute__((ext_vector_type(2)));
__device__ __forceinline__ v2f splat2(float x) { v2f r; r.x = x; r.y = x; return r; }
__device__ __forceinline__ v2f mk2(float a, float b) { v2f r; r.x = a; r.y = b; return r; }
__device__ __forceinline__ v2f pkfma(v2f a, v2f b, v2f c) { return __builtin_elementwise_fma(a, b, c); }

__device__ __forceinline__ float waveAllSum(float v) {
  #pragma unroll
  for (int m = 32; m >= 1; m >>= 1) v += __shfl_xor(v, m, 64);
  return v;
}

// ---------------------------------------------------------------------------
// K1: row-matmuls, 8 rows/block. 1-D grid, XCD-clustered: which = idx & 7
// (8 'which' values -> each weight panel lives on one XCD's L2).
//  which 0..5: P/Q projections + CA/CB (biases folded: rel_b1->P, cor_b1->CB)
//  which 6: Ca = rel_W2 @ mapWa  (xb<32), da = rel_b2 @ mapWa (xb==32)
//  which 7: Cb = rel_W2 @ mapWb  (xb<32), db = rel_b2 @ mapWb (xb==32)
// ---------------------------------------------------------------------------
__global__ __launch_bounds__(256) void k_proj(
    const float* __restrict__ srcE, const float* __restrict__ tgtE,
    const float* __restrict__ relW1, const float* __restrict__ relb1,
    const float* __restrict__ corW1, const float* __restrict__ corb1,
    const float* __restrict__ relW2, const float* __restrict__ relb2,
    const float* __restrict__ mapW1,
    float* __restrict__ Ps, float* __restrict__ Qs,
    float* __restrict__ Pt, float* __restrict__ Qt,
    float* __restrict__ CA, float* __restrict__ CB,
    float* __restrict__ Ca, float* __restrict__ Cb,
    float* __restrict__ da, float* __restrict__ db)
{
  const int which = blockIdx.x & 7;   // XCD-clustered
  const int xb    = blockIdx.x >> 3;  // [0,33)
  const int h     = threadIdx.x;
  if (which < 6 && xb >= 16) return;
  const int row0  = xb * 8;

  const float* A = nullptr; const float* W; const float* bias = nullptr;
  float* out;
  if (which == 0)      { A = srcE; W = relW1;              bias = relb1; out = Ps; }
  else if (which == 1) { A = srcE; W = relW1 + EDIM*HDIM;  out = Qs; }
  else if (which == 2) { A = tgtE; W = relW1;              bias = relb1; out = Pt; }
  else if (which == 3) { A = tgtE; W = relW1 + EDIM*HDIM;  out = Qt; }
  else if (which == 4) { A = srcE; W = corW1;              out = CA; }
  else if (which == 5) { A = tgtE; W = corW1 + EDIM*HDIM;  bias = corb1; out = CB; }
  else if (which == 6) { W = mapW1;                        out = Ca; }
  else                 { W = mapW1 + EDIM*HDIM;            out = Cb; }

  __shared__ float arow[8][EDIM];
  if (which < 6) {
    #pragma unroll
    for (int r = 0; r < 8; ++r) arow[r][h] = A[(row0 + r)*EDIM + h];
  } else if (xb < 32) {
    #pragma unroll
    for (int r = 0; r < 8; ++r) arow[r][h] = relW2[(row0 + r)*EDIM + h];
  } else {
    #pragma unroll
    for (int r = 0; r < 8; ++r) arow[r][h] = relb2[h];
  }
  __syncthreads();

  float acc[8];
  const float init = bias ? bias[h] : 0.0f;
  #pragma unroll
  for (int r = 0; r < 8; ++r) acc[r] = init;

  for (int d = 0; d < EDIM; d += 4) {
    const float w0 = W[(d+0)*HDIM + h];
    const float w1 = W[(d+1)*HDIM + h];
    const float w2 = W[(d+2)*HDIM + h];
    const float w3 = W[(d+3)*HDIM + h];
    #pragma unroll
    for (int r = 0; r < 8; ++r) {
      const float4 av = *(const float4*)&arow[r][d];
      acc[r] = fmaf(av.x,w0, fmaf(av.y,w1, fmaf(av.z,w2, fmaf(av.w,w3, acc[r]))));
    }
  }

  if (which < 6 || xb < 32) {
    #pragma unroll
    for (int r = 0; r < 8; ++r) out[(row0 + r)*HDIM + h] = acc[r];
  } else {
    float* d = (which == 6) ? da : db;
    d[h] = acc[0];
  }
}

// ---------------------------------------------------------------------------
// K2: fused rel-encode + combined projection, 8 rows/block, 512 threads.
// 1-D grid, XCD-clustered: side = idx & 1 -> even XCDs stream only Ca,
// odd XCDs only Cb (each 256 KB, L2-resident).
// rg = tid>>8 owns 4 rows; both row-groups issue IDENTICAL C addresses
// (L1 reuse). Single GEMM vs precombined C = W2 @ mapW{a,b}:
//   X = relu(LN(P+Q));  out = m_row * (X@C + d) [+ mapb1 for side1]
// Epilogue: row stats; side0 -> SAp (packed s-pairs) + SAr; side1 -> TB.
// ---------------------------------------------------------------------------
__global__ __launch_bounds__(512) void k_encode(
    const float* __restrict__ Ps, const float* __restrict__ Qs,
    const float* __restrict__ relS,
    const float* __restrict__ Pt, const float* __restrict__ Qt,
    const float* __restrict__ relT,
    const float* __restrict__ g1, const float* __restrict__ be1,
    const float* __restrict__ Ca, const float* __restrict__ Cb,
    const float* __restrict__ da, const float* __restrict__ db,
    const float* __restrict__ mapb1,
    const float* __restrict__ mapg, const float* __restrict__ mapbe,
    const float* __restrict__ mapW2,
    float2* __restrict__ SAp, float* __restrict__ SAr, float* __restrict__ TB,
    float* __restrict__ rsS, float* __restrict__ qsS,
    float* __restrict__ rsT, float* __restrict__ qsT,
    float4* __restrict__ gbw)
{
  const int side = blockIdx.x & 1;      // XCD-parity clustering
  const int bx   = blockIdx.x >> 1;     // [0,256)
  const float* P   = side ? Pt   : Ps;
  const float* Q   = side ? Qt   : Qs;
  const float* rel = side ? relT : relS;

  const int row0 = bx * 8;              // [0,2048)
  const int b   = row0 >> 8;
  const int ij0 = row0 & 255;
  const int i   = ij0 >> 4;
  const int j0  = ij0 & 15;             // 8 consecutive j, same i
  const int tid  = threadIdx.x;
  const int h    = tid & 255;
  const int rg   = tid >> 8;            // row-group: rows rg*4 .. rg*4+3
  const int wave = tid >> 6;            // 0..7
  const int lane = tid & 63;

  if (side == 0 && bx == 0 && rg == 0)
    gbw[h] = make_float4(mapg[h], mapbe[h], mapW2[h], 0.0f);

  __shared__ v2f rlp[2][2][HDIM];       // [rg][pair][h], 8 KB
  __shared__ float red[8][8];

  const float pv = P[(b*16 + i)*HDIM + h];
  float x[4];
  #pragma unroll
  for (int r = 0; r < 4; ++r) x[r] = pv + Q[(b*16 + j0 + rg*4 + r)*HDIM + h];

  // LN stats
  {
    float s1[4], s2[4];
    #pragma unroll
    for (int r = 0; r < 4; ++r) { s1[r] = x[r]; s2[r] = x[r]*x[r]; }
    #pragma unroll
    for (int m = 32; m >= 1; m >>= 1) {
      #pragma unroll
      for (int r = 0; r < 4; ++r) {
        s1[r] += __shfl_xor(s1[r], m, 64);
        s2[r] += __shfl_xor(s2[r], m, 64);
      }
    }
    if (lane == 0) {
      #pragma unroll
      for (int r = 0; r < 4; ++r) { red[wave][2*r] = s1[r]; red[wave][2*r+1] = s2[r]; }
    }
  }
  __syncthreads();

  {
    const float gh = g1[h], beh = be1[h];
    const int wb = rg*4;
    float val[4];
    #pragma unroll
    for (int r = 0; r < 4; ++r) {
      const float S1 = red[wb+0][2*r] + red[wb+1][2*r] + red[wb+2][2*r] + red[wb+3][2*r];
      const float S2 = red[wb+0][2*r+1] + red[wb+1][2*r+1] + red[wb+2][2*r+1] + red[wb+3][2*r+1];
      const float mean = S1 * (1.0f/256.0f);
      const float var  = S2 * (1.0f/256.0f) - mean*mean;
      const float rinv = rsqrtf(var + 1e-5f);
      val[r] = fmaxf(fmaf((x[r] - mean)*rinv, gh, beh), 0.0f);
    }
    rlp[rg][0][h] = mk2(val[0], val[1]);
    rlp[rg][1][h] = mk2(val[2], val[3]);
  }
  __syncthreads();

  // single GEMM vs precombined C
  const float* C = side ? Cb : Ca;
  v2f c01 = {0.f,0.f}, c23 = {0.f,0.f};
  #pragma unroll 2
  for (int k = 0; k < HDIM; k += 4) {
    const float w0 = C[(k+0)*HDIM + h];
    const float w1 = C[(k+1)*HDIM + h];
    const float w2 = C[(k+2)*HDIM + h];
    const float w3 = C[(k+3)*HDIM + h];
    const float4 pa = *(const float4*)&rlp[rg][0][k];
    const float4 pb = *(const float4*)&rlp[rg][0][k+2];
    const float4 qa = *(const float4*)&rlp[rg][1][k];
    const float4 qb = *(const float4*)&rlp[rg][1][k+2];
    c01 = pkfma(mk2(pa.x,pa.y), splat2(w0), c01);
    c01 = pkfma(mk2(pa.z,pa.w), splat2(w1), c01);
    c01 = pkfma(mk2(pb.x,pb.y), splat2(w2), c01);
    c01 = pkfma(mk2(pb.z,pb.w), splat2(w3), c01);
    c23 = pkfma(mk2(qa.x,qa.y), splat2(w0), c23);
    c23 = pkfma(mk2(qa.z,qa.w), splat2(w1), c23);
    c23 = pkfma(mk2(qb.x,qb.y), splat2(w2), c23);
    c23 = pkfma(mk2(qb.z,qb.w), splat2(w3), c23);
  }

  {
    const float dv = (side ? db : da)[h];
    c01 = c01 + splat2(dv);
    c23 = c23 + splat2(dv);
    const float* relRow = rel + (b*16 + i)*16;
    const int jb = j0 + rg*4;
    const v2f m01 = mk2(relRow[jb+0] > 0.f ? 1.f : 0.f, relRow[jb+1] > 0.f ? 1.f : 0.f);
    const v2f m23 = mk2(relRow[jb+2] > 0.f ? 1.f : 0.f, relRow[jb+3] > 0.f ? 1.f : 0.f);
    c01 = c01 * m01;
    c23 = c23 * m23;
    if (side) {
      const float mb = mapb1[h];
      c01 = c01 + splat2(mb);
      c23 = c23 + splat2(mb);
    }
  }

  // row stats of output
  {
    float s1[4] = {c01.x, c01.y, c23.x, c23.y};
    float s2[4] = {c01.x*c01.x, c01.y*c01.y, c23.x*c23.x, c23.y*c23.y};
    #pragma unroll
    for (int m = 32; m >= 1; m >>= 1) {
      #pragma unroll
      for (int r = 0; r < 4; ++r) {
        s1[r] += __shfl_xor(s1[r], m, 64);
        s2[r] += __shfl_xor(s2[r], m, 64);
      }
    }
    __syncthreads();                    // red safe to rewrite
    if (lane == 0) {
      #pragma unroll
      for (int r = 0; r < 4; ++r) { red[wave][2*r] = s1[r]; red[wave][2*r+1] = s2[r]; }
    }
  }
  __syncthreads();
  if (tid < 16) {
    const int rg2 = tid >> 3, idx = tid & 7, r = idx >> 1;
    const int wb = rg2*4;
    const float v = red[wb+0][idx] + red[wb+1][idx] + red[wb+2][idx] + red[wb+3][idx];
    float* rs = side ? rsT : rsS;
    float* qs = side ? qsT : qsS;
    const int row = row0 + rg2*4 + r;
    if (idx & 1) qs[row] = v; else rs[row] = v;
  }

  const int rbase = row0 + rg*4;
  if (side == 0) {
    const int spBase = b*128 + ((ij0 + rg*4) >> 1);
    SAp[(spBase + 0)*HDIM + h] = make_float2(c01.x, c01.y);
    SAp[(spBase + 1)*HDIM + h] = make_float2(c23.x, c23.y);
    SAr[(rbase + 0)*HDIM + h] = c01.x;
    SAr[(rbase + 1)*HDIM + h] = c01.y;
    SAr[(rbase + 2)*HDIM + h] = c23.x;
    SAr[(rbase + 3)*HDIM + h] = c23.y;
  } else {
    TB[(rbase + 0)*HDIM + h] = c01.x;
    TB[(rbase + 1)*HDIM + h] = c01.y;
    TB[(rbase + 2)*HDIM + h] = c23.x;
    TB[(rbase + 3)*HDIM + h] = c23.y;
  }
}

// ---------------------------------------------------------------------------
// K3: cross GEMM G[b][t][s] = SAr[b,s,:] . TB[b,t,:]. 32x32 tile/block.
// XCD-clustered: b = idx & 7.
// ---------------------------------------------------------------------------
__global__ __launch_bounds__(256) void k_cross(
    const float* __restrict__ SAr, const float* __restrict__ TB,
    float* __restrict__ G)
{
  const int b    = blockIdx.x & 7;
  const int rest = blockIdx.x >> 3;     // [0,64)
  const int s0 = (rest & 7) * 32;
  const int t0 = (rest >> 3) * 32;
  const int tx = threadIdx.x & 15;      // s-sub
  const int ty = threadIdx.x >> 4;      // t-sub

  const float* SAb = SAr + ((b<<8) + s0)*HDIM;
  const float* TBb = TB  + ((b<<8) + t0)*HDIM;

  __shared__ float As[32][68], Bs[32][68];
  float acc00 = 0.f, acc01 = 0.f, acc10 = 0.f, acc11 = 0.f;

  const int lr = threadIdx.x >> 3;        // 0..31
  const int lc = (threadIdx.x & 7) * 8;   // 0..56

  for (int kk = 0; kk < HDIM; kk += 64) {
    *(float4*)&As[lr][lc]   = *(const float4*)&SAb[lr*HDIM + kk + lc];
    *(float4*)&As[lr][lc+4] = *(const float4*)&SAb[lr*HDIM + kk + lc + 4];
    *(float4*)&Bs[lr][lc]   = *(const float4*)&TBb[lr*HDIM + kk + lc];
    *(float4*)&Bs[lr][lc+4] = *(const float4*)&TBb[lr*HDIM + kk + lc + 4];
    __syncthreads();
    #pragma unroll
    for (int k = 0; k < 64; k += 4) {
      const float4 a0 = *(const float4*)&As[tx][k];
      const float4 a1 = *(const float4*)&As[tx+16][k];
      const float4 b0 = *(const float4*)&Bs[ty][k];
      const float4 b1 = *(const float4*)&Bs[ty+16][k];
      acc00 = fmaf(a0.x,b0.x, fmaf(a0.y,b0.y, fmaf(a0.z,b0.z, fmaf(a0.w,b0.w, acc00))));
      acc01 = fmaf(a0.x,b1.x, fmaf(a0.y,b1.y, fmaf(a0.z,b1.z, fmaf(a0.w,b1.w, acc01))));
      acc10 = fmaf(a1.x,b0.x, fmaf(a1.y,b0.y, fmaf(a1.z,b0.z, fmaf(a1.w,b0.w, acc10))));
      acc11 = fmaf(a1.x,b1.x, fmaf(a1.y,b1.y, fmaf(a1.z,b1.z, fmaf(a1.w,b1.w, acc11))));
    }
    __syncthreads();
  }

  float* Gb = G + (((b<<8) + t0)<<8) + s0;     // G[b][t][s]
  Gb[(ty   )*256 + tx     ] = acc00;
  Gb[(ty   )*256 + tx + 16] = acc10;
  Gb[(ty+16)*256 + tx     ] = acc01;
  Gb[(ty+16)*256 + tx + 16] = acc11;
}

// ---------------------------------------------------------------------------
// K4: fused scores, 256-thread blocks (4 waves), single pass over TB.
// Blocks [0,512): mapping, XCD-clustered: b = blockIdx & 7 (all 64 blocks
//   of a batch share one XCD; TBb+SApb+Gb ~2.5 MB -> L2-resident).
//   Block = (b, 4 s); wave = t-quarter; lane owns one t row of TB
//   (contiguous float4 stream). G precomputed -> al/bt up front; SAp/gbw on
//   the scalar path; two packed accumulator chains. Softmax fused in-block.
// Blocks [512,544): corr scores, wave = one (b,s), softmax over 16.
// map_b2 / cor_b2 cancel in softmax -> dropped.
// ---------------------------------------------------------------------------
__global__ __launch_bounds__(256) void k_scores(
    const float2* __restrict__ SApf, const float* __restrict__ TB,
    const float* __restrict__ G,
    const float* __restrict__ rsS, const float* __restrict__ qsS,
    const float* __restrict__ rsT, const float* __restrict__ qsT,
    const float4* __restrict__ gbw,
    const float* __restrict__ CA, const float* __restrict__ CB,
    const float* __restrict__ cW2,
    float* __restrict__ mapOut, float* __restrict__ corOut)
{
  const int wave = threadIdx.x >> 6;
  const int lane = threadIdx.x & 63;

  if (blockIdx.x >= 512) {
    const int bs = (blockIdx.x - 512)*4 + wave;
    const int b  = bs >> 4;
    const float4 ca4 = *(const float4*)(CA + bs*HDIM + lane*4);
    const float4 w24 = *(const float4*)(cW2 + lane*4);
    float sc[16];
    #pragma unroll
    for (int t = 0; t < 16; ++t) {
      const float4 cb4 = *(const float4*)(CB + (b*16 + t)*HDIM + lane*4);
      float p = fmaxf(ca4.x + cb4.x, 0.0f)*w24.x
              + fmaxf(ca4.y + cb4.y, 0.0f)*w24.y
              + fmaxf(ca4.z + cb4.z, 0.0f)*w24.z
              + fmaxf(ca4.w + cb4.w, 0.0f)*w24.w;
      sc[t] = waveAllSum(p);
    }
    float mx = sc[0];
    #pragma unroll
    for (int t = 1; t < 16; ++t) mx = fmaxf(mx, sc[t]);
    float se = 0.0f;
    #pragma unroll
    for (int t = 0; t < 16; ++t) { sc[t] = __expf(sc[t] - mx); se += sc[t]; }
    if (lane < 16) corOut[bs*16 + lane] = sc[lane] / se;
    return;
  }

  // XCD-clustered decode: batch = low 3 bits -> one XCD per batch
  const int b  = blockIdx.x & 7;
  const int s0 = (blockIdx.x >> 3) * 4;      // [0,256) step 4
  const int t  = (wave << 6) + lane;

  const float* tbrow = TB + ((b<<8) + t)*HDIM;
  const v2f* sp0 = (const v2f*)SApf + ((b<<7) + (s0>>1))*HDIM;
  const v2f* sp1 = sp0 + HDIM;

  v2f al01, bt01, al23, bt23;
  {
    const float4 gv = *(const float4*)&G[(((b<<8) + t)<<8) + s0];
    const float rt = rsT[(b<<8) + t];
    const float qt = qsT[(b<<8) + t];
    const float Gv[4] = {gv.x, gv.y, gv.z, gv.w};
    float alv[4], btv[4];
    #pragma unroll
    for (int si = 0; si < 4; ++si) {
      const float mean = (rsS[(b<<8) + s0 + si] + rt) * (1.0f/256.0f);
      const float e2   = (qsS[(b<<8) + s0 + si] + qt + 2.0f*Gv[si]) * (1.0f/256.0f);
      const float rinv = rsqrtf(e2 - mean*mean + 1e-5f);
      alv[si] = rinv;
      btv[si] = -mean * rinv;
    }
    al01 = mk2(alv[0], alv[1]); bt01 = mk2(btv[0], btv[1]);
    al23 = mk2(alv[2], alv[3]); bt23 = mk2(btv[2], btv[3]);
  }

  v2f acc01 = {0.f,0.f}, acc23 = {0.f,0.f};
  const v2f zero = {0.f,0.f};
  #pragma unroll 2
  for (int h = 0; h < HDIM; h += 4) {
    const float4 tb4 = *(const float4*)&tbrow[h];
    const v2f a0 = sp0[h], a1 = sp0[h+1], a2 = sp0[h+2], a3 = sp0[h+3];
    const v2f c0 = sp1[h], c1 = sp1[h+1], c2 = sp1[h+2], c3 = sp1[h+3];
    const float4 q0 = gbw[h], q1 = gbw[h+1], q2 = gbw[h+2], q3 = gbw[h+3];
    v2f u, r;
    u = pkfma(a0 + splat2(tb4.x), al01, bt01);
    r = __builtin_elementwise_max(pkfma(u, splat2(q0.x), splat2(q0.y)), zero);
    acc01 = pkfma(r, splat2(q0.z), acc01);
    u = pkfma(c0 + splat2(tb4.x), al23, bt23);
    r = __builtin_elementwise_max(pkfma(u, splat2(q0.x), splat2(q0.y)), zero);
    acc23 = pkfma(r, splat2(q0.z), acc23);

    u = pkfma(a1 + splat2(tb4.y), al01, bt01);
    r = __builtin_elementwise_max(pkfma(u, splat2(q1.x), splat2(q1.y)), zero);
    acc01 = pkfma(r, splat2(q1.z), acc01);
    u = pkfma(c1 + splat2(tb4.y), al23, bt23);
    r = __builtin_elementwise_max(pkfma(u, splat2(q1.x), splat2(q1.y)), zero);
    acc23 = pkfma(r, splat2(q1.z), acc23);

    u = pkfma(a2 + splat2(tb4.z), al01, bt01);
    r = __builtin_elementwise_max(pkfma(u, splat2(q2.x), splat2(q2.y)), zero);
    acc01 = pkfma(r, splat2(q2.z), acc01);
    u = pkfma(c2 + splat2(tb4.z), al23, bt23);
    r = __builtin_elementwise_max(pkfma(u, splat2(q2.x), splat2(q2.y)), zero);
    acc23 = pkfma(r, splat2(q2.z), acc23);

    u = pkfma(a3 + splat2(tb4.w), al01, bt01);
    r = __builtin_elementwise_max(pkfma(u, splat2(q3.x), splat2(q3.y)), zero);
    acc01 = pkfma(r, splat2(q3.z), acc01);
    u = pkfma(c3 + splat2(tb4.w), al23, bt23);
    r = __builtin_elementwise_max(pkfma(u, splat2(q3.x), splat2(q3.y)), zero);
    acc23 = pkfma(r, splat2(q3.z), acc23);
  }

  __shared__ float sc[4][256];
  sc[0][t] = acc01.x; sc[1][t] = acc01.y; sc[2][t] = acc23.x; sc[3][t] = acc23.y;
  __syncthreads();

  float v0 = sc[wave][lane];
  float v1 = sc[wave][lane + 64];
  float v2 = sc[wave][lane + 128];
  float v3 = sc[wave][lane + 192];
  float mx = fmaxf(fmaxf(v0, v1), fmaxf(v2, v3));
  #pragma unroll
  for (int m = 32; m >= 1; m >>= 1) mx = fmaxf(mx, __shfl_xor(mx, m, 64));
  const float e0 = __expf(v0 - mx), e1 = __expf(v1 - mx);
  const float e2 = __expf(v2 - mx), e3 = __expf(v3 - mx);
  const float se = waveAllSum(e0 + e1 + e2 + e3);
  const float inv = 1.0f / se;
  float* orow = mapOut + ((b<<8) + s0 + wave)*256;
  orow[lane]       = e0 * inv;
  orow[lane + 64]  = e1 * inv;
  orow[lane + 128] = e2 * inv;
  orow[lane + 192] = e3 * inv;
}

extern "C" void kernel_launch(void* const* d_in, const int* in_sizes, int n_in,
                              void* d_out, int out_size, void* d_ws, size_t ws_size,
                              hipStream_t stream) {
  const float* srcE  = (const float*)d_in[0];
  const float* srcR  = (const float*)d_in[1];
  const float* tgtE  = (const float*)d_in[2];
  const float* tgtR  = (const float*)d_in[3];
  const float* relW1 = (const float*)d_in[4];
  const float* relb1 = (const float*)d_in[5];
  const float* relg1 = (const float*)d_in[6];
  const float* relbe1= (const float*)d_in[7];
  const float* relW2 = (const float*)d_in[8];
  const float* relb2 = (const float*)d_in[9];
  const float* mapW1 = (const float*)d_in[10];
  const float* mapb1 = (const float*)d_in[11];
  const float* mapg  = (const float*)d_in[12];
  const float* mapbe = (const float*)d_in[13];
  const float* mapW2 = (const float*)d_in[14];
  const float* corW1 = (const float*)d_in[16];
  const float* corb1 = (const float*)d_in[17];
  const float* corW2 = (const float*)d_in[18];

  float* ws   = (float*)d_ws;
  float* Ps   = ws;                 // 32768 each
  float* Qs   = Ps   + 32768;
  float* Pt   = Qs   + 32768;
  float* Qt   = Pt   + 32768;
  float* CA   = Qt   + 32768;
  float* CB   = CA   + 32768;
  float2* SAp = (float2*)(CB + 32768);          // 262144 float2 = 524288 f
  float* SAr  = (float*)(SAp + 262144);         // 524288 f
  float* TB   = SAr + 524288;                   // 524288 f
  float* G    = TB  + 524288;                   // 524288 f
  float* rsS  = G + 524288;         // 2048
  float* qsS  = rsS + 2048;
  float* rsT  = qsS + 2048;
  float* qsT  = rsT + 2048;
  float4* gbw = (float4*)(qsT + 2048);          // 256 float4 = 1024 f
  float* Ca   = (float*)gbw + 1024;             // 65536
  float* Cb   = Ca + 65536;                     // 65536
  float* da   = Cb + 65536;                     // 256
  float* db   = da + 256;                       // 256

  float* mapOut = (float*)d_out;        // 524288
  float* corOut = mapOut + 524288;      // 2048

  k_proj<<<264, 256, 0, stream>>>(srcE, tgtE, relW1, relb1, corW1, corb1,
                                  relW2, relb2, mapW1,
                                  Ps, Qs, Pt, Qt, CA, CB,
                                  Ca, Cb, da, db);
  k_encode<<<512, 512, 0, stream>>>(Ps, Qs, srcR,
                                    Pt, Qt, tgtR,
                                    relg1, relbe1,
                                    Ca, Cb, da, db,
                                    mapb1, mapg, mapbe, mapW2,
                                    SAp, SAr, TB, rsS, qsS, rsT, qsT, gbw);
  k_cross<<<512, 256, 0, stream>>>(SAr, TB, G);
  k_scores<<<544, 256, 0, stream>>>(SAp, TB, G, rsS, qsS, rsT, qsT, gbw,
                                    CA, CB, corW2, mapOut, corOut);
}

// Round 15
// 67.017 us; speedup vs baseline: 1.1912x; 1.0236x over previous
//
#include <hip/hip_runtime.h>

#define EDIM 256
#define HDIM 256

typedef float v2f __attribute__((ext_vector_type(2)));
__device__ __forceinline__ v2f splat2(float x) { v2f r; r.x = x; r.y = x; return r; }
__device__ __forceinline__ v2f mk2(float a, float b) { v2f r; r.x = a; r.y = b; return r; }
__device__ __forceinline__ v2f pkfma(v2f a, v2f b, v2f c) { return __builtin_elementwise_fma(a, b, c); }

__device__ __forceinline__ float waveAllSum(float v) {
  #pragma unroll
  for (int m = 32; m >= 1; m >>= 1) v += __shfl_xor(v, m, 64);
  return v;
}

// ---------------------------------------------------------------------------
// K1: row-matmuls, 8 rows/block. 1-D grid, XCD-clustered: which = idx & 7.
// ---------------------------------------------------------------------------
__global__ __launch_bounds__(256) void k_proj(
    const float* __restrict__ srcE, const float* __restrict__ tgtE,
    const float* __restrict__ relW1, const float* __restrict__ relb1,
    const float* __restrict__ corW1, const float* __restrict__ corb1,
    const float* __restrict__ relW2, const float* __restrict__ relb2,
    const float* __restrict__ mapW1,
    float* __restrict__ Ps, float* __restrict__ Qs,
    float* __restrict__ Pt, float* __restrict__ Qt,
    float* __restrict__ CA, float* __restrict__ CB,
    float* __restrict__ Ca, float* __restrict__ Cb,
    float* __restrict__ da, float* __restrict__ db)
{
  const int which = blockIdx.x & 7;   // XCD-clustered
  const int xb    = blockIdx.x >> 3;  // [0,33)
  const int h     = threadIdx.x;
  if (which < 6 && xb >= 16) return;
  const int row0  = xb * 8;

  const float* A = nullptr; const float* W; const float* bias = nullptr;
  float* out;
  if (which == 0)      { A = srcE; W = relW1;              bias = relb1; out = Ps; }
  else if (which == 1) { A = srcE; W = relW1 + EDIM*HDIM;  out = Qs; }
  else if (which == 2) { A = tgtE; W = relW1;              bias = relb1; out = Pt; }
  else if (which == 3) { A = tgtE; W = relW1 + EDIM*HDIM;  out = Qt; }
  else if (which == 4) { A = srcE; W = corW1;              out = CA; }
  else if (which == 5) { A = tgtE; W = corW1 + EDIM*HDIM;  bias = corb1; out = CB; }
  else if (which == 6) { W = mapW1;                        out = Ca; }
  else                 { W = mapW1 + EDIM*HDIM;            out = Cb; }

  __shared__ float arow[8][EDIM];
  if (which < 6) {
    #pragma unroll
    for (int r = 0; r < 8; ++r) arow[r][h] = A[(row0 + r)*EDIM + h];
  } else if (xb < 32) {
    #pragma unroll
    for (int r = 0; r < 8; ++r) arow[r][h] = relW2[(row0 + r)*EDIM + h];
  } else {
    #pragma unroll
    for (int r = 0; r < 8; ++r) arow[r][h] = relb2[h];
  }
  __syncthreads();

  float acc[8];
  const float init = bias ? bias[h] : 0.0f;
  #pragma unroll
  for (int r = 0; r < 8; ++r) acc[r] = init;

  for (int d = 0; d < EDIM; d += 4) {
    const float w0 = W[(d+0)*HDIM + h];
    const float w1 = W[(d+1)*HDIM + h];
    const float w2 = W[(d+2)*HDIM + h];
    const float w3 = W[(d+3)*HDIM + h];
    #pragma unroll
    for (int r = 0; r < 8; ++r) {
      const float4 av = *(const float4*)&arow[r][d];
      acc[r] = fmaf(av.x,w0, fmaf(av.y,w1, fmaf(av.z,w2, fmaf(av.w,w3, acc[r]))));
    }
  }

  if (which < 6 || xb < 32) {
    #pragma unroll
    for (int r = 0; r < 8; ++r) out[(row0 + r)*HDIM + h] = acc[r];
  } else {
    float* d = (which == 6) ? da : db;
    d[h] = acc[0];
  }
}

// ---------------------------------------------------------------------------
// K2: fused rel-encode + combined projection, 8 rows/block, 512 threads.
// 1-D grid, XCD-clustered: side = idx & 1.
// ---------------------------------------------------------------------------
__global__ __launch_bounds__(512) void k_encode(
    const float* __restrict__ Ps, const float* __restrict__ Qs,
    const float* __restrict__ relS,
    const float* __restrict__ Pt, const float* __restrict__ Qt,
    const float* __restrict__ relT,
    const float* __restrict__ g1, const float* __restrict__ be1,
    const float* __restrict__ Ca, const float* __restrict__ Cb,
    const float* __restrict__ da, const float* __restrict__ db,
    const float* __restrict__ mapb1,
    const float* __restrict__ mapg, const float* __restrict__ mapbe,
    const float* __restrict__ mapW2,
    float2* __restrict__ SAp, float* __restrict__ SAr, float* __restrict__ TB,
    float* __restrict__ rsS, float* __restrict__ qsS,
    float* __restrict__ rsT, float* __restrict__ qsT,
    float4* __restrict__ gbw)
{
  const int side = blockIdx.x & 1;      // XCD-parity clustering
  const int bx   = blockIdx.x >> 1;     // [0,256)
  const float* P   = side ? Pt   : Ps;
  const float* Q   = side ? Qt   : Qs;
  const float* rel = side ? relT : relS;

  const int row0 = bx * 8;              // [0,2048)
  const int b   = row0 >> 8;
  const int ij0 = row0 & 255;
  const int i   = ij0 >> 4;
  const int j0  = ij0 & 15;             // 8 consecutive j, same i
  const int tid  = threadIdx.x;
  const int h    = tid & 255;
  const int rg   = tid >> 8;            // row-group: rows rg*4 .. rg*4+3
  const int wave = tid >> 6;            // 0..7
  const int lane = tid & 63;

  if (side == 0 && bx == 0 && rg == 0)
    gbw[h] = make_float4(mapg[h], mapbe[h], mapW2[h], 0.0f);

  __shared__ v2f rlp[2][2][HDIM];       // [rg][pair][h], 8 KB
  __shared__ float red[8][8];

  const float pv = P[(b*16 + i)*HDIM + h];
  float x[4];
  #pragma unroll
  for (int r = 0; r < 4; ++r) x[r] = pv + Q[(b*16 + j0 + rg*4 + r)*HDIM + h];

  // LN stats
  {
    float s1[4], s2[4];
    #pragma unroll
    for (int r = 0; r < 4; ++r) { s1[r] = x[r]; s2[r] = x[r]*x[r]; }
    #pragma unroll
    for (int m = 32; m >= 1; m >>= 1) {
      #pragma unroll
      for (int r = 0; r < 4; ++r) {
        s1[r] += __shfl_xor(s1[r], m, 64);
        s2[r] += __shfl_xor(s2[r], m, 64);
      }
    }
    if (lane == 0) {
      #pragma unroll
      for (int r = 0; r < 4; ++r) { red[wave][2*r] = s1[r]; red[wave][2*r+1] = s2[r]; }
    }
  }
  __syncthreads();

  {
    const float gh = g1[h], beh = be1[h];
    const int wb = rg*4;
    float val[4];
    #pragma unroll
    for (int r = 0; r < 4; ++r) {
      const float S1 = red[wb+0][2*r] + red[wb+1][2*r] + red[wb+2][2*r] + red[wb+3][2*r];
      const float S2 = red[wb+0][2*r+1] + red[wb+1][2*r+1] + red[wb+2][2*r+1] + red[wb+3][2*r+1];
      const float mean = S1 * (1.0f/256.0f);
      const float var  = S2 * (1.0f/256.0f) - mean*mean;
      const float rinv = rsqrtf(var + 1e-5f);
      val[r] = fmaxf(fmaf((x[r] - mean)*rinv, gh, beh), 0.0f);
    }
    rlp[rg][0][h] = mk2(val[0], val[1]);
    rlp[rg][1][h] = mk2(val[2], val[3]);
  }
  __syncthreads();

  // single GEMM vs precombined C
  const float* C = side ? Cb : Ca;
  v2f c01 = {0.f,0.f}, c23 = {0.f,0.f};
  #pragma unroll 2
  for (int k = 0; k < HDIM; k += 4) {
    const float w0 = C[(k+0)*HDIM + h];
    const float w1 = C[(k+1)*HDIM + h];
    const float w2 = C[(k+2)*HDIM + h];
    const float w3 = C[(k+3)*HDIM + h];
    const float4 pa = *(const float4*)&rlp[rg][0][k];
    const float4 pb = *(const float4*)&rlp[rg][0][k+2];
    const float4 qa = *(const float4*)&rlp[rg][1][k];
    const float4 qb = *(const float4*)&rlp[rg][1][k+2];
    c01 = pkfma(mk2(pa.x,pa.y), splat2(w0), c01);
    c01 = pkfma(mk2(pa.z,pa.w), splat2(w1), c01);
    c01 = pkfma(mk2(pb.x,pb.y), splat2(w2), c01);
    c01 = pkfma(mk2(pb.z,pb.w), splat2(w3), c01);
    c23 = pkfma(mk2(qa.x,qa.y), splat2(w0), c23);
    c23 = pkfma(mk2(qa.z,qa.w), splat2(w1), c23);
    c23 = pkfma(mk2(qb.x,qb.y), splat2(w2), c23);
    c23 = pkfma(mk2(qb.z,qb.w), splat2(w3), c23);
  }

  {
    const float dv = (side ? db : da)[h];
    c01 = c01 + splat2(dv);
    c23 = c23 + splat2(dv);
    const float* relRow = rel + (b*16 + i)*16;
    const int jb = j0 + rg*4;
    const v2f m01 = mk2(relRow[jb+0] > 0.f ? 1.f : 0.f, relRow[jb+1] > 0.f ? 1.f : 0.f);
    const v2f m23 = mk2(relRow[jb+2] > 0.f ? 1.f : 0.f, relRow[jb+3] > 0.f ? 1.f : 0.f);
    c01 = c01 * m01;
    c23 = c23 * m23;
    if (side) {
      const float mb = mapb1[h];
      c01 = c01 + splat2(mb);
      c23 = c23 + splat2(mb);
    }
  }

  // row stats of output
  {
    float s1[4] = {c01.x, c01.y, c23.x, c23.y};
    float s2[4] = {c01.x*c01.x, c01.y*c01.y, c23.x*c23.x, c23.y*c23.y};
    #pragma unroll
    for (int m = 32; m >= 1; m >>= 1) {
      #pragma unroll
      for (int r = 0; r < 4; ++r) {
        s1[r] += __shfl_xor(s1[r], m, 64);
        s2[r] += __shfl_xor(s2[r], m, 64);
      }
    }
    __syncthreads();                    // red safe to rewrite
    if (lane == 0) {
      #pragma unroll
      for (int r = 0; r < 4; ++r) { red[wave][2*r] = s1[r]; red[wave][2*r+1] = s2[r]; }
    }
  }
  __syncthreads();
  if (tid < 16) {
    const int rg2 = tid >> 3, idx = tid & 7, r = idx >> 1;
    const int wb = rg2*4;
    const float v = red[wb+0][idx] + red[wb+1][idx] + red[wb+2][idx] + red[wb+3][idx];
    float* rs = side ? rsT : rsS;
    float* qs = side ? qsT : qsS;
    const int row = row0 + rg2*4 + r;
    if (idx & 1) qs[row] = v; else rs[row] = v;
  }

  const int rbase = row0 + rg*4;
  if (side == 0) {
    const int spBase = b*128 + ((ij0 + rg*4) >> 1);
    SAp[(spBase + 0)*HDIM + h] = make_float2(c01.x, c01.y);
    SAp[(spBase + 1)*HDIM + h] = make_float2(c23.x, c23.y);
    SAr[(rbase + 0)*HDIM + h] = c01.x;
    SAr[(rbase + 1)*HDIM + h] = c01.y;
    SAr[(rbase + 2)*HDIM + h] = c23.x;
    SAr[(rbase + 3)*HDIM + h] = c23.y;
  } else {
    TB[(rbase + 0)*HDIM + h] = c01.x;
    TB[(rbase + 1)*HDIM + h] = c01.y;
    TB[(rbase + 2)*HDIM + h] = c23.x;
    TB[(rbase + 3)*HDIM + h] = c23.y;
  }
}

// ---------------------------------------------------------------------------
// K3: cross GEMM G[b][t][s] = SAr[b,s,:] . TB[b,t,:]. 32x32 tile/block.
// XCD-clustered: b = idx & 7.
// ---------------------------------------------------------------------------
__global__ __launch_bounds__(256) void k_cross(
    const float* __restrict__ SAr, const float* __restrict__ TB,
    float* __restrict__ G)
{
  const int b    = blockIdx.x & 7;
  const int rest = blockIdx.x >> 3;     // [0,64)
  const int s0 = (rest & 7) * 32;
  const int t0 = (rest >> 3) * 32;
  const int tx = threadIdx.x & 15;      // s-sub
  const int ty = threadIdx.x >> 4;      // t-sub

  const float* SAb = SAr + ((b<<8) + s0)*HDIM;
  const float* TBb = TB  + ((b<<8) + t0)*HDIM;

  __shared__ float As[32][68], Bs[32][68];
  float acc00 = 0.f, acc01 = 0.f, acc10 = 0.f, acc11 = 0.f;

  const int lr = threadIdx.x >> 3;        // 0..31
  const int lc = (threadIdx.x & 7) * 8;   // 0..56

  for (int kk = 0; kk < HDIM; kk += 64) {
    *(float4*)&As[lr][lc]   = *(const float4*)&SAb[lr*HDIM + kk + lc];
    *(float4*)&As[lr][lc+4] = *(const float4*)&SAb[lr*HDIM + kk + lc + 4];
    *(float4*)&Bs[lr][lc]   = *(const float4*)&TBb[lr*HDIM + kk + lc];
    *(float4*)&Bs[lr][lc+4] = *(const float4*)&TBb[lr*HDIM + kk + lc + 4];
    __syncthreads();
    #pragma unroll
    for (int k = 0; k < 64; k += 4) {
      const float4 a0 = *(const float4*)&As[tx][k];
      const float4 a1 = *(const float4*)&As[tx+16][k];
      const float4 b0 = *(const float4*)&Bs[ty][k];
      const float4 b1 = *(const float4*)&Bs[ty+16][k];
      acc00 = fmaf(a0.x,b0.x, fmaf(a0.y,b0.y, fmaf(a0.z,b0.z, fmaf(a0.w,b0.w, acc00))));
      acc01 = fmaf(a0.x,b1.x, fmaf(a0.y,b1.y, fmaf(a0.z,b1.z, fmaf(a0.w,b1.w, acc01))));
      acc10 = fmaf(a1.x,b0.x, fmaf(a1.y,b0.y, fmaf(a1.z,b0.z, fmaf(a1.w,b0.w, acc10))));
      acc11 = fmaf(a1.x,b1.x, fmaf(a1.y,b1.y, fmaf(a1.z,b1.z, fmaf(a1.w,b1.w, acc11))));
    }
    __syncthreads();
  }

  float* Gb = G + (((b<<8) + t0)<<8) + s0;     // G[b][t][s]
  Gb[(ty   )*256 + tx     ] = acc00;
  Gb[(ty   )*256 + tx + 16] = acc10;
  Gb[(ty+16)*256 + tx     ] = acc01;
  Gb[(ty+16)*256 + tx + 16] = acc11;
}

// ---------------------------------------------------------------------------
// K4: fused scores, 512-thread blocks (8 waves), h-split with SCALAR-PATH
// REPAIR. Blocks [0,512): mapping, XCD-clustered (b = idx & 7). Block =
//   (b, 4 s). Wave = (hw, tq): tq = t-quarter (lane owns t-row), hw = h-half
//   (128 iters). h0 goes through readfirstlane -> compiler keeps SAp/gbw on
//   the scalar pipe (fixes R7's divergence demotion). Two v2f s-chains per
//   lane (proven R9 ILP). Partials via 8 KB LDS. Softmax fused (waves 0-3).
// Blocks [512,528): corr scores, wave = one (b,s), softmax over 16.
// ---------------------------------------------------------------------------
__global__ __launch_bounds__(512) void k_scores(
    const float2* __restrict__ SApf, const float* __restrict__ TB,
    const float* __restrict__ G,
    const float* __restrict__ rsS, const float* __restrict__ qsS,
    const float* __restrict__ rsT, const float* __restrict__ qsT,
    const float4* __restrict__ gbw,
    const float* __restrict__ CA, const float* __restrict__ CB,
    const float* __restrict__ cW2,
    float* __restrict__ mapOut, float* __restrict__ corOut)
{
  const int wave = threadIdx.x >> 6;
  const int lane = threadIdx.x & 63;

  if (blockIdx.x >= 512) {
    // ---- corr: 16 blocks x 8 waves; wave handles one bs in [0,128) ----
    const int bs = (blockIdx.x - 512)*8 + wave;
    const int b  = bs >> 4;
    const float4 ca4 = *(const float4*)(CA + bs*HDIM + lane*4);
    const float4 w24 = *(const float4*)(cW2 + lane*4);
    float sc[16];
    #pragma unroll
    for (int t = 0; t < 16; ++t) {
      const float4 cb4 = *(const float4*)(CB + (b*16 + t)*HDIM + lane*4);
      float p = fmaxf(ca4.x + cb4.x, 0.0f)*w24.x
              + fmaxf(ca4.y + cb4.y, 0.0f)*w24.y
              + fmaxf(ca4.z + cb4.z, 0.0f)*w24.z
              + fmaxf(ca4.w + cb4.w, 0.0f)*w24.w;
      sc[t] = waveAllSum(p);
    }
    float mx = sc[0];
    #pragma unroll
    for (int t = 1; t < 16; ++t) mx = fmaxf(mx, sc[t]);
    float se = 0.0f;
    #pragma unroll
    for (int t = 0; t < 16; ++t) { sc[t] = __expf(sc[t] - mx); se += sc[t]; }
    if (lane < 16) corOut[bs*16 + lane] = sc[lane] / se;
    return;
  }

  // XCD-clustered decode: batch = low 3 bits -> one XCD per batch
  const int b  = blockIdx.x & 7;
  const int s0 = (blockIdx.x >> 3) * 4;      // [0,256) step 4
  const int tq = wave & 3;                   // t-quarter
  const int hw = wave >> 2;                  // h-half
  const int t  = (tq << 6) + lane;
  const int h0 = __builtin_amdgcn_readfirstlane(hw * 128);  // wave-uniform

  const float* tbrow = TB + ((b<<8) + t)*HDIM;
  const v2f* sp0 = (const v2f*)SApf + ((b<<7) + (s0>>1))*HDIM;
  const v2f* sp1 = sp0 + HDIM;

  v2f al01, bt01, al23, bt23;
  {
    const float4 gv = *(const float4*)&G[(((b<<8) + t)<<8) + s0];
    const float rt = rsT[(b<<8) + t];
    const float qt = qsT[(b<<8) + t];
    const float Gv[4] = {gv.x, gv.y, gv.z, gv.w};
    float alv[4], btv[4];
    #pragma unroll
    for (int si = 0; si < 4; ++si) {
      const float mean = (rsS[(b<<8) + s0 + si] + rt) * (1.0f/256.0f);
      const float e2   = (qsS[(b<<8) + s0 + si] + qt + 2.0f*Gv[si]) * (1.0f/256.0f);
      const float rinv = rsqrtf(e2 - mean*mean + 1e-5f);
      alv[si] = rinv;
      btv[si] = -mean * rinv;
    }
    al01 = mk2(alv[0], alv[1]); bt01 = mk2(btv[0], btv[1]);
    al23 = mk2(alv[2], alv[3]); bt23 = mk2(btv[2], btv[3]);
  }

  v2f acc01 = {0.f,0.f}, acc23 = {0.f,0.f};
  const v2f zero = {0.f,0.f};
  #pragma unroll 2
  for (int h = h0; h < h0 + 128; h += 4) {
    const float4 tb4 = *(const float4*)&tbrow[h];
    const v2f a0 = sp0[h], a1 = sp0[h+1], a2 = sp0[h+2], a3 = sp0[h+3];
    const v2f c0 = sp1[h], c1 = sp1[h+1], c2 = sp1[h+2], c3 = sp1[h+3];
    const float4 q0 = gbw[h], q1 = gbw[h+1], q2 = gbw[h+2], q3 = gbw[h+3];
    v2f u, r;
    u = pkfma(a0 + splat2(tb4.x), al01, bt01);
    r = __builtin_elementwise_max(pkfma(u, splat2(q0.x), splat2(q0.y)), zero);
    acc01 = pkfma(r, splat2(q0.z), acc01);
    u = pkfma(c0 + splat2(tb4.x), al23, bt23);
    r = __builtin_elementwise_max(pkfma(u, splat2(q0.x), splat2(q0.y)), zero);
    acc23 = pkfma(r, splat2(q0.z), acc23);

    u = pkfma(a1 + splat2(tb4.y), al01, bt01);
    r = __builtin_elementwise_max(pkfma(u, splat2(q1.x), splat2(q1.y)), zero);
    acc01 = pkfma(r, splat2(q1.z), acc01);
    u = pkfma(c1 + splat2(tb4.y), al23, bt23);
    r = __builtin_elementwise_max(pkfma(u, splat2(q1.x), splat2(q1.y)), zero);
    acc23 = pkfma(r, splat2(q1.z), acc23);

    u = pkfma(a2 + splat2(tb4.z), al01, bt01);
    r = __builtin_elementwise_max(pkfma(u, splat2(q2.x), splat2(q2.y)), zero);
    acc01 = pkfma(r, splat2(q2.z), acc01);
    u = pkfma(c2 + splat2(tb4.z), al23, bt23);
    r = __builtin_elementwise_max(pkfma(u, splat2(q2.x), splat2(q2.y)), zero);
    acc23 = pkfma(r, splat2(q2.z), acc23);

    u = pkfma(a3 + splat2(tb4.w), al01, bt01);
    r = __builtin_elementwise_max(pkfma(u, splat2(q3.x), splat2(q3.y)), zero);
    acc01 = pkfma(r, splat2(q3.z), acc01);
    u = pkfma(c3 + splat2(tb4.w), al23, bt23);
    r = __builtin_elementwise_max(pkfma(u, splat2(q3.x), splat2(q3.y)), zero);
    acc23 = pkfma(r, splat2(q3.z), acc23);
  }

  // combine h-halves, then softmax
  __shared__ float pg[2][4][4][64];          // [hw][tq][si][lane], 8 KB
  pg[hw][tq][0][lane] = acc01.x;
  pg[hw][tq][1][lane] = acc01.y;
  pg[hw][tq][2][lane] = acc23.x;
  pg[hw][tq][3][lane] = acc23.y;
  __syncthreads();

  __shared__ float sc[4][256];
  if (hw == 0) {
    sc[0][t] = pg[0][tq][0][lane] + pg[1][tq][0][lane];
    sc[1][t] = pg[0][tq][1][lane] + pg[1][tq][1][lane];
    sc[2][t] = pg[0][tq][2][lane] + pg[1][tq][2][lane];
    sc[3][t] = pg[0][tq][3][lane] + pg[1][tq][3][lane];
  }
  __syncthreads();

  if (wave < 4) {                            // wave w -> s = s0 + w
    float v0 = sc[wave][lane];
    float v1 = sc[wave][lane + 64];
    float v2 = sc[wave][lane + 128];
    float v3 = sc[wave][lane + 192];
    float mx = fmaxf(fmaxf(v0, v1), fmaxf(v2, v3));
    #pragma unroll
    for (int m = 32; m >= 1; m >>= 1) mx = fmaxf(mx, __shfl_xor(mx, m, 64));
    const float e0 = __expf(v0 - mx), e1 = __expf(v1 - mx);
    const float e2 = __expf(v2 - mx), e3 = __expf(v3 - mx);
    const float se = waveAllSum(e0 + e1 + e2 + e3);
    const float inv = 1.0f / se;
    float* orow = mapOut + ((b<<8) + s0 + wave)*256;
    orow[lane]       = e0 * inv;
    orow[lane + 64]  = e1 * inv;
    orow[lane + 128] = e2 * inv;
    orow[lane + 192] = e3 * inv;
  }
}

extern "C" void kernel_launch(void* const* d_in, const int* in_sizes, int n_in,
                              void* d_out, int out_size, void* d_ws, size_t ws_size,
                              hipStream_t stream) {
  const float* srcE  = (const float*)d_in[0];
  const float* srcR  = (const float*)d_in[1];
  const float* tgtE  = (const float*)d_in[2];
  const float* tgtR  = (const float*)d_in[3];
  const float* relW1 = (const float*)d_in[4];
  const float* relb1 = (const float*)d_in[5];
  const float* relg1 = (const float*)d_in[6];
  const float* relbe1= (const float*)d_in[7];
  const float* relW2 = (const float*)d_in[8];
  const float* relb2 = (const float*)d_in[9];
  const float* mapW1 = (const float*)d_in[10];
  const float* mapb1 = (const float*)d_in[11];
  const float* mapg  = (const float*)d_in[12];
  const float* mapbe = (const float*)d_in[13];
  const float* mapW2 = (const float*)d_in[14];
  const float* corW1 = (const float*)d_in[16];
  const float* corb1 = (const float*)d_in[17];
  const float* corW2 = (const float*)d_in[18];

  float* ws   = (float*)d_ws;
  float* Ps   = ws;                 // 32768 each
  float* Qs   = Ps   + 32768;
  float* Pt   = Qs   + 32768;
  float* Qt   = Pt   + 32768;
  float* CA   = Qt   + 32768;
  float* CB   = CA   + 32768;
  float2* SAp = (float2*)(CB + 32768);          // 262144 float2 = 524288 f
  float* SAr  = (float*)(SAp + 262144);         // 524288 f
  float* TB   = SAr + 524288;                   // 524288 f
  float* G    = TB  + 524288;                   // 524288 f
  float* rsS  = G + 524288;         // 2048
  float* qsS  = rsS + 2048;
  float* rsT  = qsS + 2048;
  float* qsT  = rsT + 2048;
  float4* gbw = (float4*)(qsT + 2048);          // 256 float4 = 1024 f
  float* Ca   = (float*)gbw + 1024;             // 65536
  float* Cb   = Ca + 65536;                     // 65536
  float* da   = Cb + 65536;                     // 256
  float* db   = da + 256;                       // 256

  float* mapOut = (float*)d_out;        // 524288
  float* corOut = mapOut + 524288;      // 2048

  k_proj<<<264, 256, 0, stream>>>(srcE, tgtE, relW1, relb1, corW1, corb1,
                                  relW2, relb2, mapW1,
                                  Ps, Qs, Pt, Qt, CA, CB,
                                  Ca, Cb, da, db);
  k_encode<<<512, 512, 0, stream>>>(Ps, Qs, srcR,
                                    Pt, Qt, tgtR,
                                    relg1, relbe1,
                                    Ca, Cb, da, db,
                                    mapb1, mapg, mapbe, mapW2,
                                    SAp, SAr, TB, rsS, qsS, rsT, qsT, gbw);
  k_cross<<<512, 256, 0, stream>>>(SAr, TB, G);
  k_scores<<<528, 512, 0, stream>>>(SAp, TB, G, rsS, qsS, rsT, qsT, gbw,
                                    CA, CB, corW2, mapOut, corOut);
}